// Round 6
// baseline (38.928 us; speedup 1.0000x reference)
//
#include <hip/hip_runtime.h>

#define N_NODES 4096
#define DEG 8
#define N_EDGES (N_NODES * DEG)
#define FEAT 64
#define HID 32
#define NC 2
#define N_SEEDS 512
#define BCAP 32          // in-degree bucket cap; P(Poisson(8) >= 32) ~ 4e-11/node

#define GEMM_BLOCKS 512          // 512*256 = 131072 = N_NODES*HID
#define BUILD_BLOCKS 128         // 128*256 = 32768 = N_EDGES
#define D1_BLOCKS (GEMM_BLOCKS + BUILD_BLOCKS)
#define D2_BLOCKS 512

// ws layout:
//   Z1  [0,     512K)   float[4096*32]
//   Z2  [512K,  544K)   float[4096*2]
//   r   [544K,  560K)   int[4096]        (in-degree; memset to 0 each call)
//   cnt [560K,  560K+4) int               (D2 done-counter; same memset)
//   bkt [576K,  832K)   ushort[4096*32]  (incoming-edge source nodes)

// D1: blocks [0,512): Z1 = X@W1 (W1 in LDS). blocks [512,640): transpose build.
__global__ __launch_bounds__(256) void d1_gemm_build(
        const float* __restrict__ X, const float* __restrict__ W1,
        const int* __restrict__ ind,
        float* __restrict__ Z1, int* __restrict__ r,
        unsigned short* __restrict__ bkt) {
    __shared__ float W1s[FEAT * HID];
    int b = blockIdx.x, t = threadIdx.x;
    if (b < GEMM_BLOCKS) {
        for (int i = t; i < FEAT * HID; i += 256) W1s[i] = W1[i];
        __syncthreads();
        int idx = b * 256 + t;                 // n*32 + h
        int n = idx >> 5, h = idx & 31;
        const float4* x4 = (const float4*)(X + n * FEAT);
        float acc = 0.f;
#pragma unroll
        for (int q = 0; q < 16; ++q) {
            float4 xv = x4[q];
            acc += xv.x * W1s[(4 * q + 0) * HID + h];
            acc += xv.y * W1s[(4 * q + 1) * HID + h];
            acc += xv.z * W1s[(4 * q + 2) * HID + h];
            acc += xv.w * W1s[(4 * q + 3) * HID + h];
        }
        Z1[idx] = acc;
    } else {
        int e = (b - GEMM_BLOCKS) * 256 + t;   // 0..32767
        int u = e >> 3;                         // uniform CSR: indptr[n]=n*DEG
        int v = ind[e];
        if (v != u) {
            int slot = atomicAdd(&r[v], 1);
            if (slot < BCAP) bkt[v * BCAP + slot] = (unsigned short)u;
        }
    }
}

// D2: hop1 gather + fused Z2 = relu(A1+b1)@W2; last block does hop2@seeds + out.
__global__ __launch_bounds__(256) void d2_hop1_out(
        const float* __restrict__ Z1, const int* __restrict__ ind,
        const int* __restrict__ r, const unsigned short* __restrict__ bkt,
        const float* __restrict__ pb1, const float* __restrict__ W2,
        const float* __restrict__ pb2, const int* __restrict__ seed,
        float* __restrict__ Z2, int* __restrict__ cnt,
        float* __restrict__ out) {
    int idx = blockIdx.x * 256 + threadIdx.x;  // n*32 + h
    int n = idx >> 5, h = idx & 31;
    float zn = Z1[idx];
    int rn = r[n];
    float a = (float)(DEG + rn) * zn;

    // outgoing: vector-load CSR row, issue all 8 gathers, masked accumulate
    const int4* rp = (const int4*)(ind + n * DEG);
    int4 ra = rp[0], rb = rp[1];
    int vs[8] = {ra.x, ra.y, ra.z, ra.w, rb.x, rb.y, rb.z, rb.w};
    float zv[8];
#pragma unroll
    for (int d = 0; d < 8; ++d) zv[d] = Z1[vs[d] * HID + h];
#pragma unroll
    for (int d = 0; d < 8; ++d) a += (vs[d] != n) ? zv[d] : 0.f;

    // incoming: vector-load full 64B bucket row, sanitized unconditional gathers
    const uint4* bp = (const uint4*)(bkt + n * BCAP);
    uint4 w0 = bp[0], w1 = bp[1], w2 = bp[2], w3 = bp[3];
    unsigned wd[16] = {w0.x, w0.y, w0.z, w0.w, w1.x, w1.y, w1.z, w1.w,
                       w2.x, w2.y, w2.z, w2.w, w3.x, w3.y, w3.z, w3.w};
#pragma unroll
    for (int j = 0; j < 16; ++j) {
        int u0 = (int)(wd[j] & 0xFFFu) ;           // sanitized (garbage-safe)
        int u1 = (int)((wd[j] >> 16) & 0xFFFu);
        float z0 = Z1[u0 * HID + h];
        float z1 = Z1[u1 * HID + h];
        a += (2 * j     < rn) ? z0 : 0.f;
        a += (2 * j + 1 < rn) ? z1 : 0.f;
    }

    // fused layer-2: Z2[n][c] = relu(a+b1) @ W2 via 32-lane shuffle reduce
    float hk = a + pb1[h];
    hk = hk > 0.f ? hk : 0.f;
    float t0 = hk * W2[h * NC + 0];
    float t1 = hk * W2[h * NC + 1];
#pragma unroll
    for (int off = 16; off > 0; off >>= 1) {
        t0 += __shfl_down(t0, off, 32);
        t1 += __shfl_down(t1, off, 32);
    }
    if (h == 0) *(float2*)(Z2 + n * NC) = make_float2(t0, t1);

    // ---- last-block: hop2 at seed nodes + output ----
    __shared__ int last;
    __syncthreads();
    if (threadIdx.x == 0) {
        __threadfence();                       // release Z2 writes
        int old = atomicAdd(cnt, 1);
        last = (old == D2_BLOCKS - 1) ? 1 : 0;
    }
    __syncthreads();
    if (!last) return;
    __threadfence();                           // acquire other blocks' Z2

    for (int s = threadIdx.x; s < N_SEEDS; s += 256) {
        int n2 = seed[s];
        int rn2 = r[n2];
        float2 z = *(const float2*)(Z2 + n2 * NC);
        float c0 = (float)(DEG + rn2);
        float a0 = c0 * z.x, a1 = c0 * z.y;
        const int4* rp2 = (const int4*)(ind + n2 * DEG);
        int4 sa = rp2[0], sb = rp2[1];
        int vs2[8] = {sa.x, sa.y, sa.z, sa.w, sb.x, sb.y, sb.z, sb.w};
#pragma unroll
        for (int d = 0; d < 8; ++d) {
            float2 tv = *(const float2*)(Z2 + vs2[d] * NC);
            if (vs2[d] != n2) { a0 += tv.x; a1 += tv.y; }
        }
        const uint4* bp2 = (const uint4*)(bkt + n2 * BCAP);
        uint4 q0 = bp2[0], q1 = bp2[1], q2 = bp2[2], q3 = bp2[3];
        unsigned qd[16] = {q0.x, q0.y, q0.z, q0.w, q1.x, q1.y, q1.z, q1.w,
                           q2.x, q2.y, q2.z, q2.w, q3.x, q3.y, q3.z, q3.w};
#pragma unroll
        for (int j = 0; j < 16; ++j) {
            int u0 = (int)(qd[j] & 0xFFFu);
            int u1 = (int)((qd[j] >> 16) & 0xFFFu);
            float2 t0v = *(const float2*)(Z2 + u0 * NC);
            float2 t1v = *(const float2*)(Z2 + u1 * NC);
            if (2 * j     < rn2) { a0 += t0v.x; a1 += t0v.y; }
            if (2 * j + 1 < rn2) { a0 += t1v.x; a1 += t1v.y; }
        }
        out[s * NC + 0] = a0 + pb2[0];
        out[s * NC + 1] = a1 + pb2[1];
    }
}

extern "C" void kernel_launch(void* const* d_in, const int* in_sizes, int n_in,
                              void* d_out, int out_size, void* d_ws, size_t ws_size,
                              hipStream_t stream) {
    // setup_inputs order: sub_indptr, sub_indices, X, W1, b1, W2, b2, seed_idx
    const int*   ind  = (const int*)d_in[1];
    const float* X    = (const float*)d_in[2];
    const float* W1   = (const float*)d_in[3];
    const float* b1   = (const float*)d_in[4];
    const float* W2   = (const float*)d_in[5];
    const float* b2   = (const float*)d_in[6];
    const int*   seed = (const int*)d_in[7];
    float* out = (float*)d_out;

    char* ws = (char*)d_ws;
    float*          Z1  = (float*)(ws);
    float*          Z2  = (float*)(ws + 512 * 1024);
    int*            r   = (int*)(ws + 544 * 1024);
    int*            cnt = (int*)(ws + 560 * 1024);
    unsigned short* bkt = (unsigned short*)(ws + 576 * 1024);

    // zero r (16 KiB) + cnt (adjacent) in one cheap memset node
    hipMemsetAsync(r, 0, 16 * 1024 + 64, stream);
    d1_gemm_build<<<D1_BLOCKS, 256, 0, stream>>>(X, W1, ind, Z1, r, bkt);
    d2_hop1_out  <<<D2_BLOCKS, 256, 0, stream>>>(Z1, ind, r, bkt, b1, W2, b2,
                                                 seed, Z2, cnt, out);
}

// Round 7
// 21.947 us; speedup vs baseline: 1.7737x; 1.7737x over previous
//
#include <hip/hip_runtime.h>

#define N_NODES 4096
#define DEG 8
#define N_EDGES (N_NODES * DEG)
#define FEAT 64
#define HID 32
#define NC 2
#define N_SEEDS 512
#define BCAP 32   // in-degree cap; actual max for this fixed input ≪ 32

// ws layout:
//   Z1  [0,     512K)  float[4096*32]
//   Z2  [512K,  544K)  float[4096*2]
//   r   [544K,  560K)  int[4096]
//   bkt [576K,  832K)  ushort[4096*32]

// K1: Z1 = X@W1 (W1 in LDS, float4 X loads); zero in-degree counters.
__global__ __launch_bounds__(256) void k1_gemm(const float* __restrict__ X,
                                               const float* __restrict__ W1,
                                               float* __restrict__ Z1,
                                               int* __restrict__ r) {
    __shared__ float W1s[FEAT * HID];
    int t = threadIdx.x;
    for (int i = t; i < FEAT * HID; i += 256) W1s[i] = W1[i];
    __syncthreads();
    int idx = blockIdx.x * 256 + t;        // n*32 + h
    int n = idx >> 5, h = idx & 31;
    const float4* x4 = (const float4*)(X + n * FEAT);
    float acc = 0.f;
#pragma unroll
    for (int q = 0; q < 16; ++q) {
        float4 xv = x4[q];
        acc += xv.x * W1s[(4 * q + 0) * HID + h];
        acc += xv.y * W1s[(4 * q + 1) * HID + h];
        acc += xv.z * W1s[(4 * q + 2) * HID + h];
        acc += xv.w * W1s[(4 * q + 3) * HID + h];
    }
    Z1[idx] = acc;
    if (idx < N_NODES) r[idx] = 0;
}

// K2: transpose adjacency build (32K int atomics).
__global__ __launch_bounds__(256) void k2_build(const int* __restrict__ ind,
                                                int* __restrict__ r,
                                                unsigned short* __restrict__ bkt) {
    int e = blockIdx.x * 256 + threadIdx.x;   // 0..32767
    int u = e >> 3;                            // uniform CSR: indptr[n]=n*DEG
    int v = ind[e];
    if (v != u) {
        int slot = atomicAdd(&r[v], 1);
        if (slot < BCAP) bkt[v * BCAP + slot] = (unsigned short)u;
    }
}

// K3: hop-1 gather (all loads issued up front, masked accumulate) + fused
// Z2 = relu(A1+b1)@W2 via 32-lane shuffle reduce.
__global__ __launch_bounds__(256) void k3_hop1(const float* __restrict__ Z1,
                                               const int* __restrict__ ind,
                                               const int* __restrict__ r,
                                               const unsigned short* __restrict__ bkt,
                                               const float* __restrict__ pb1,
                                               const float* __restrict__ W2,
                                               float* __restrict__ Z2) {
    int idx = blockIdx.x * 256 + threadIdx.x;  // n*32 + h
    int n = idx >> 5, h = idx & 31;

    // issue all index loads first (independent)
    const int4* rp = (const int4*)(ind + n * DEG);
    int4 ra = rp[0], rb = rp[1];
    const uint4* bp = (const uint4*)(bkt + n * BCAP);
    uint4 w0 = bp[0], w1 = bp[1];              // 16 bucket entries (covers rn<=16)
    int rn = r[n];
    float zn = Z1[idx];

    int vs[8] = {ra.x, ra.y, ra.z, ra.w, rb.x, rb.y, rb.z, rb.w};
    float zv[8];
#pragma unroll
    for (int d = 0; d < 8; ++d) zv[d] = Z1[vs[d] * HID + h];

    unsigned wd[8] = {w0.x, w0.y, w0.z, w0.w, w1.x, w1.y, w1.z, w1.w};
    float zi[16];
#pragma unroll
    for (int j = 0; j < 8; ++j) {
        zi[2 * j]     = Z1[(int)(wd[j] & 0xFFFu) * HID + h];
        zi[2 * j + 1] = Z1[(int)((wd[j] >> 16) & 0xFFFu) * HID + h];
    }

    float a = (float)(DEG + rn) * zn;
#pragma unroll
    for (int d = 0; d < 8; ++d) a += (vs[d] != n) ? zv[d] : 0.f;
    int rc = rn < BCAP ? rn : BCAP;
#pragma unroll
    for (int j = 0; j < 16; ++j) a += (j < rc) ? zi[j] : 0.f;

    if (rc > 16) {                              // P ~ 0.4% of nodes
        uint4 w2v = bp[2], w3v = bp[3];
        unsigned we[8] = {w2v.x, w2v.y, w2v.z, w2v.w, w3v.x, w3v.y, w3v.z, w3v.w};
#pragma unroll
        for (int j = 0; j < 8; ++j) {
            int b0 = 16 + 2 * j;
            float z0 = Z1[(int)(we[j] & 0xFFFu) * HID + h];
            float z1 = Z1[(int)((we[j] >> 16) & 0xFFFu) * HID + h];
            a += (b0     < rc) ? z0 : 0.f;
            a += (b0 + 1 < rc) ? z1 : 0.f;
        }
    }

    // fused layer-2
    float hk = a + pb1[h];
    hk = hk > 0.f ? hk : 0.f;
    float t0 = hk * W2[h * NC + 0];
    float t1 = hk * W2[h * NC + 1];
#pragma unroll
    for (int off = 16; off > 0; off >>= 1) {
        t0 += __shfl_down(t0, off, 32);
        t1 += __shfl_down(t1, off, 32);
    }
    if (h == 0) *(float2*)(Z2 + n * NC) = make_float2(t0, t1);
}

// K4: hop-2 at seed nodes only, one thread per seed (both classes).
__global__ __launch_bounds__(256) void k4_out(const float* __restrict__ Z2,
                                              const int* __restrict__ ind,
                                              const int* __restrict__ r,
                                              const unsigned short* __restrict__ bkt,
                                              const float* __restrict__ pb2,
                                              const int* __restrict__ seed,
                                              float* __restrict__ out) {
    int s = blockIdx.x * 256 + threadIdx.x;
    if (s >= N_SEEDS) return;
    int n = seed[s];

    const int4* rp = (const int4*)(ind + n * DEG);
    int4 ra = rp[0], rb = rp[1];
    const uint4* bp = (const uint4*)(bkt + n * BCAP);
    uint4 w0 = bp[0], w1 = bp[1];
    int rn = r[n];
    float2 z = *(const float2*)(Z2 + n * NC);

    int vs[8] = {ra.x, ra.y, ra.z, ra.w, rb.x, rb.y, rb.z, rb.w};
    float2 zv[8];
#pragma unroll
    for (int d = 0; d < 8; ++d) zv[d] = *(const float2*)(Z2 + vs[d] * NC);

    unsigned wd[8] = {w0.x, w0.y, w0.z, w0.w, w1.x, w1.y, w1.z, w1.w};
    float2 zi[16];
#pragma unroll
    for (int j = 0; j < 8; ++j) {
        zi[2 * j]     = *(const float2*)(Z2 + (int)(wd[j] & 0xFFFu) * NC);
        zi[2 * j + 1] = *(const float2*)(Z2 + (int)((wd[j] >> 16) & 0xFFFu) * NC);
    }

    float c0 = (float)(DEG + rn);
    float a0 = c0 * z.x, a1 = c0 * z.y;
#pragma unroll
    for (int d = 0; d < 8; ++d)
        if (vs[d] != n) { a0 += zv[d].x; a1 += zv[d].y; }
    int rc = rn < BCAP ? rn : BCAP;
#pragma unroll
    for (int j = 0; j < 16; ++j)
        if (j < rc) { a0 += zi[j].x; a1 += zi[j].y; }

    if (rc > 16) {
        uint4 w2v = bp[2], w3v = bp[3];
        unsigned we[8] = {w2v.x, w2v.y, w2v.z, w2v.w, w3v.x, w3v.y, w3v.z, w3v.w};
#pragma unroll
        for (int j = 0; j < 8; ++j) {
            int b0 = 16 + 2 * j;
            float2 z0 = *(const float2*)(Z2 + (int)(we[j] & 0xFFFu) * NC);
            float2 z1 = *(const float2*)(Z2 + (int)((we[j] >> 16) & 0xFFFu) * NC);
            if (b0     < rc) { a0 += z0.x; a1 += z0.y; }
            if (b0 + 1 < rc) { a0 += z1.x; a1 += z1.y; }
        }
    }

    out[s * NC + 0] = a0 + pb2[0];
    out[s * NC + 1] = a1 + pb2[1];
}

extern "C" void kernel_launch(void* const* d_in, const int* in_sizes, int n_in,
                              void* d_out, int out_size, void* d_ws, size_t ws_size,
                              hipStream_t stream) {
    // setup_inputs order: sub_indptr, sub_indices, X, W1, b1, W2, b2, seed_idx
    const int*   ind  = (const int*)d_in[1];
    const float* X    = (const float*)d_in[2];
    const float* W1   = (const float*)d_in[3];
    const float* b1   = (const float*)d_in[4];
    const float* W2   = (const float*)d_in[5];
    const float* b2   = (const float*)d_in[6];
    const int*   seed = (const int*)d_in[7];
    float* out = (float*)d_out;

    char* ws = (char*)d_ws;
    float*          Z1  = (float*)(ws);
    float*          Z2  = (float*)(ws + 512 * 1024);
    int*            r   = (int*)(ws + 544 * 1024);
    unsigned short* bkt = (unsigned short*)(ws + 576 * 1024);

    k1_gemm <<<(N_NODES * HID) / 256, 256, 0, stream>>>(X, W1, Z1, r);
    k2_build<<<N_EDGES / 256,        256, 0, stream>>>(ind, r, bkt);
    k3_hop1 <<<(N_NODES * HID) / 256, 256, 0, stream>>>(Z1, ind, r, bkt, b1, W2, Z2);
    k4_out  <<<(N_SEEDS + 255) / 256, 256, 0, stream>>>(Z2, ind, r, bkt, b2, seed, out);
}